// Round 1
// baseline (1031.303 us; speedup 1.0000x reference)
//
#include <hip/hip_runtime.h>
#include <hip/hip_bf16.h>
#include <math.h>

// Problem: S=128, B=16, D=H=512, O=256.
// Collapse: watch/sus are exactly s-independent (zero init + [B,H] broadcast),
// so the scan is a [16,512] recurrence; outs is a broadcast of [128,16,256].

#define S_LEN 128
#define B_SZ  16
#define H_SZ  512
#define O_SZ  256
#define ROWS  (S_LEN * B_SZ)   // 2048

#define OUTS_ELEMS  (S_LEN * S_LEN * B_SZ * O_SZ)   // 67,108,864
#define WATCH_ELEMS (S_LEN * B_SZ * H_SZ)           // 1,048,576

// workspace layout (float offsets)
#define WS_FLAGS 0
#define WS_CBUF  256
#define WS_WALL  (WS_CBUF + ROWS * H_SZ)
#define WS_TMP   (WS_WALL + ROWS * H_SZ)
#define WS_MBUF  (WS_TMP + ROWS * H_SZ)

typedef __bf16 bf16x8 __attribute__((ext_vector_type(8)));
typedef float  f32x4  __attribute__((ext_vector_type(4)));

// ---------------- generic tiled f32 GEMM: C[M,N] = A[M,K]@B[K,N] + b0 + b1 ---
__global__ __launch_bounds__(256) void gemm_f32(
    const float* __restrict__ A, const float* __restrict__ B,
    const float* __restrict__ b0, const float* __restrict__ b1,
    float* __restrict__ C, int N, int K)
{
  __shared__ float As[16][65];
  __shared__ float Bs[16][65];
  const int bm = blockIdx.y << 6, bn = blockIdx.x << 6;
  const int tx = threadIdx.x & 15, ty = threadIdx.x >> 4;
  float acc[4][4] = {};
  for (int k0 = 0; k0 < K; k0 += 16) {
    for (int i = threadIdx.x; i < 1024; i += 256) {
      const int r = i >> 4, kk = i & 15;
      As[kk][r] = A[(bm + r) * K + k0 + kk];
    }
    for (int i = threadIdx.x; i < 1024; i += 256) {
      const int kk = i >> 6, n = i & 63;
      Bs[kk][n] = B[(k0 + kk) * N + bn + n];
    }
    __syncthreads();
#pragma unroll
    for (int kk = 0; kk < 16; ++kk) {
      float a[4], bb[4];
#pragma unroll
      for (int i = 0; i < 4; ++i) a[i] = As[kk][(ty << 2) + i];
#pragma unroll
      for (int j = 0; j < 4; ++j) bb[j] = Bs[kk][(tx << 2) + j];
#pragma unroll
      for (int i = 0; i < 4; ++i)
#pragma unroll
        for (int j = 0; j < 4; ++j) acc[i][j] += a[i] * bb[j];
    }
    __syncthreads();
  }
#pragma unroll
  for (int i = 0; i < 4; ++i) {
    const int row = bm + (ty << 2) + i;
#pragma unroll
    for (int j = 0; j < 4; ++j) {
      const int col = bn + (tx << 2) + j;
      float r = acc[i][j];
      if (b0) r += b0[col];
      if (b1) r += b1[col];
      C[row * N + col] = r;
    }
  }
}

// ---------------- softmax over H then gate by x (in-place on logits) --------
__global__ __launch_bounds__(64) void softmax_gate(float* __restrict__ lg,
                                                   const float* __restrict__ x)
{
  const int r = blockIdx.x;      // 0..2047
  const int lane = threadIdx.x;  // 0..63
  float v[8];
  float m = -1e30f;
#pragma unroll
  for (int i = 0; i < 8; ++i) {
    v[i] = lg[(r << 9) + (i << 6) + lane];
    m = fmaxf(m, v[i]);
  }
#pragma unroll
  for (int off = 32; off > 0; off >>= 1) m = fmaxf(m, __shfl_xor(m, off, 64));
  float s = 0.f;
#pragma unroll
  for (int i = 0; i < 8; ++i) { v[i] = expf(v[i] - m); s += v[i]; }
#pragma unroll
  for (int off = 32; off > 0; off >>= 1) s += __shfl_xor(s, off, 64);
  const float inv = 1.0f / s;
#pragma unroll
  for (int i = 0; i < 8; ++i) {
    const int idx = (r << 9) + (i << 6) + lane;
    lg[idx] = v[i] * inv * x[idx];
  }
}

// ---------------- persistent recurrence: w_t = tanh(c_t + w_{t-1} @ ins_w) --
// 32 WGs x 256 thr; WG j owns cols [16j,16j+16) of ins_w as split-bf16 MFMA
// B-fragments in registers. Exchange w_t via global, monotonic epoch flags.
#define NWG_R 32
#define CWG   16

__global__ __launch_bounds__(256) void recurrence(
    const float* __restrict__ cbuf,   // [128][16][512]
    const float* __restrict__ insw,   // [512][512]
    float* __restrict__ wall,         // [128][16][512]
    unsigned* __restrict__ flags)     // [32], zeroed before launch
{
  __shared__ float wsm[B_SZ][516];   // staged w_{t-1}, padded stride
  __shared__ float red[4][256];      // inter-wave reduction

  const int wg   = blockIdx.x;
  const int c0   = wg * CWG;
  const int tid  = threadIdx.x;
  const int wv   = tid >> 6;         // wave 0..3 (K range 128*wv)
  const int lane = tid & 63;
  const int frow = lane & 15;        // A row / B col / D col
  const int fgrp = lane >> 4;        // k-group 0..3

  // preload B fragments hi/lo for this wave's K range (once)
  bf16x8 bhi[4], blo[4];
#pragma unroll
  for (int s = 0; s < 4; ++s) {
#pragma unroll
    for (int j = 0; j < 8; ++j) {
      const int k = (wv << 7) + (s << 5) + (fgrp << 3) + j;
      const float w = insw[(k << 9) + c0 + frow];
      const __bf16 h = (__bf16)w;
      bhi[s][j] = h;
      blo[s][j] = (__bf16)(w - (float)h);
    }
  }

  const int ob = tid >> 4;           // output b 0..15
  const int oc = tid & 15;           // output c 0..15
  const int gcol = c0 + oc;

  // t = 0: w0 = tanh(c0)
  {
    const float v = tanhf(cbuf[(ob << 9) + gcol]);
    wall[(ob << 9) + gcol] = v;
  }
  __syncthreads();                   // drains vmcnt before barrier
  if (tid == 0) {
    __threadfence();
    __hip_atomic_store(&flags[wg], 1u, __ATOMIC_RELEASE, __HIP_MEMORY_SCOPE_AGENT);
  }

  for (int t = 1; t < S_LEN; ++t) {
    // wait until every WG finished step t-1 (flags monotonic, no reset races)
    if (tid < NWG_R) {
      while (__hip_atomic_load(&flags[tid], __ATOMIC_ACQUIRE,
                               __HIP_MEMORY_SCOPE_AGENT) < (unsigned)t) {}
    }
    __syncthreads();
    // stage w_{t-1} (coalesced float4)
    {
      const float4* src = (const float4*)(wall + ((t - 1) << 13));
      for (int i4 = tid; i4 < 2048; i4 += 256) {
        const int flat = i4 << 2;
        *(float4*)&wsm[flat >> 9][flat & 511] = src[i4];
      }
    }
    __syncthreads();
    // split-bf16 MFMA partials over this wave's K range
    f32x4 acc_h = {0.f, 0.f, 0.f, 0.f}, acc_l = {0.f, 0.f, 0.f, 0.f};
#pragma unroll
    for (int s = 0; s < 4; ++s) {
      const int kbase = (wv << 7) + (s << 5) + (fgrp << 3);
      bf16x8 ahi, alo;
#pragma unroll
      for (int j = 0; j < 8; ++j) {
        const float w = wsm[frow][kbase + j];
        const __bf16 h = (__bf16)w;
        ahi[j] = h;
        alo[j] = (__bf16)(w - (float)h);
      }
      acc_h = __builtin_amdgcn_mfma_f32_16x16x32_bf16(ahi, bhi[s], acc_h, 0, 0, 0);
      acc_l = __builtin_amdgcn_mfma_f32_16x16x32_bf16(alo, bhi[s], acc_l, 0, 0, 0);
      acc_l = __builtin_amdgcn_mfma_f32_16x16x32_bf16(ahi, blo[s], acc_l, 0, 0, 0);
    }
#pragma unroll
    for (int r = 0; r < 4; ++r)
      red[wv][((fgrp << 2) + r) * 16 + frow] = acc_h[r] + acc_l[r];
    __syncthreads();
    // reduce across waves + tanh + publish
    {
      const float y = red[0][tid] + red[1][tid] + red[2][tid] + red[3][tid];
      const float v = tanhf(cbuf[(t << 13) + (ob << 9) + gcol] + y);
      wall[(t << 13) + (ob << 9) + gcol] = v;
    }
    __syncthreads();                 // all wall stores drained
    if (tid == 0) {
      __threadfence();               // agent-scope: L2 writeback for other XCDs
      __hip_atomic_store(&flags[wg], (unsigned)(t + 1), __ATOMIC_RELEASE,
                         __HIP_MEMORY_SCOPE_AGENT);
    }
  }
}

// ---------------- sus scan (elementwise over t) + watch/sus broadcast -------
__global__ __launch_bounds__(256) void sus_scan_watch(
    const float* __restrict__ M, const float* __restrict__ wall,
    float* __restrict__ watch_out, float* __restrict__ sus_out)
{
  const int tid = blockIdx.x * blockDim.x + threadIdx.x;  // 8192
  const int b = tid >> 9, h = tid & 511;
  float s = 0.f;
  for (int t = 0; t < S_LEN; ++t)
    s = tanhf(M[(t << 13) + (b << 9) + h] + s);
  const float w = wall[(127 << 13) + (b << 9) + h];
  for (int si = 0; si < S_LEN; ++si) {
    watch_out[(si << 13) + (b << 9) + h] = w;
    sus_out[(si << 13) + (b << 9) + h] = s;
  }
}

// ---------------- outs broadcast: outs[t,s,b,o] = os[t,b,o] -----------------
__global__ __launch_bounds__(256) void broadcast_outs(
    const float4* __restrict__ os4, float4* __restrict__ outs4)
{
  const int stride = gridDim.x * blockDim.x;
  for (int i = blockIdx.x * blockDim.x + threadIdx.x; i < (1 << 24); i += stride) {
    const int o4 = i & 63;
    const int b  = (i >> 6) & 15;
    const int t  = i >> 17;
    outs4[i] = os4[(((t << 4) + b) << 6) + o4];
  }
}

extern "C" void kernel_launch(void* const* d_in, const int* in_sizes, int n_in,
                              void* d_out, int out_size, void* d_ws, size_t ws_size,
                              hipStream_t stream)
{
  const float* x      = (const float*)d_in[0];
  const float* attn_w = (const float*)d_in[1];
  const float* attn_b = (const float*)d_in[2];
  const float* in_w   = (const float*)d_in[3];
  const float* in_b   = (const float*)d_in[4];
  const float* ins_w  = (const float*)d_in[5];
  const float* ins_b  = (const float*)d_in[6];
  const float* sus_w  = (const float*)d_in[7];
  const float* sus_b  = (const float*)d_in[8];
  const float* out_w  = (const float*)d_in[9];
  const float* out_b  = (const float*)d_in[10];

  float* ws    = (float*)d_ws;
  float* cbuf  = ws + WS_CBUF;
  float* wallb = ws + WS_WALL;
  float* tmp   = ws + WS_TMP;
  float* mbuf  = ws + WS_MBUF;
  unsigned* flags = (unsigned*)d_ws;

  float* outp   = (float*)d_out;
  float* watchp = outp + OUTS_ELEMS;
  float* susp   = watchp + WATCH_ELEMS;

  hipMemsetAsync(d_ws, 0, 256 * sizeof(float), stream);

  const dim3 blk(256);
  // logits = X @ attn_w + attn_b
  gemm_f32<<<dim3(8, 32), blk, 0, stream>>>(x, attn_w, attn_b, nullptr, tmp, 512, 512);
  // R = softmax(logits) * X   (in place on tmp)
  softmax_gate<<<dim3(2048), dim3(64), 0, stream>>>(tmp, x);
  // c = R @ in_w + in_b + ins_b
  gemm_f32<<<dim3(8, 32), blk, 0, stream>>>(tmp, in_w, in_b, ins_b, cbuf, 512, 512);
  // sequential: w_t = tanh(c_t + w_{t-1} @ ins_w)
  recurrence<<<dim3(NWG_R), blk, 0, stream>>>(cbuf, ins_w, wallb, flags);
  // M = W_all @ sus_w + sus_b  (carry-independent part of sus)
  gemm_f32<<<dim3(8, 32), blk, 0, stream>>>(wallb, sus_w, sus_b, nullptr, mbuf, 512, 512);
  // sus scan + watch/sus broadcast into d_out
  sus_scan_watch<<<dim3(32), blk, 0, stream>>>(mbuf, wallb, watchp, susp);
  // out_small = W_all @ out_w + out_b
  gemm_f32<<<dim3(4, 32), blk, 0, stream>>>(wallb, out_w, out_b, nullptr, mbuf, 256, 512);
  // outs broadcast (268 MB, the HBM floor of this problem)
  broadcast_outs<<<dim3(2048), blk, 0, stream>>>((const float4*)mbuf, (float4*)d_out);
}